// Round 1
// baseline (404.885 us; speedup 1.0000x reference)
//
#include <hip/hip_runtime.h>

typedef unsigned short u16;
using u16x4  = __attribute__((ext_vector_type(4))) unsigned short;
using bf16x8 = __attribute__((ext_vector_type(8))) short;
using f32x4  = __attribute__((ext_vector_type(4))) float;

// ---------- helpers ----------
__device__ __forceinline__ u16 f2bf(float f) {
  union { float f; unsigned u; } v; v.f = f;
  unsigned r = v.u + 0x7FFFu + ((v.u >> 16) & 1u);  // RNE (inputs bounded, no NaN)
  return (u16)(r >> 16);
}

__device__ __forceinline__ void async16(const u16* g, u16* l) {
  __builtin_amdgcn_global_load_lds(
      (const __attribute__((address_space(1))) void*)g,
      (__attribute__((address_space(3))) void*)l, 16, 0, 0);
}

// ---------- pre-pass 1: x fp32 -> bf16 ----------
__global__ void convert_x_k(const float* __restrict__ in, u16* __restrict__ out) {
  int i = blockIdx.x * 256 + threadIdx.x;      // one float4 per thread, 512 blocks
  float4 v = ((const float4*)in)[i];
  u16x4 u;
  u.x = f2bf(v.x); u.y = f2bf(v.y); u.z = f2bf(v.z); u.w = f2bf(v.w);
  ((u16x4*)out)[i] = u;
}

// ---------- pre-pass 2: W [mat][i][h] fp32 -> WT blocked bf16 [mat][i/32][h][32] ----------
// output element (n=h, k=i) at mat*65536 + (k>>5)*8192 + n*32 + (k&31)
__global__ void transpose_w_k(const float* __restrict__ in, u16* __restrict__ out) {
  __shared__ float tile[64][65];
  const int mat = blockIdx.x >> 4;
  const int tl  = blockIdx.x & 15;
  const int i0 = (tl >> 2) * 64, h0 = (tl & 3) * 64;
  const float* src = in + mat * 65536;
  u16* dst = out + mat * 65536;
  const int t = threadIdx.x;
#pragma unroll
  for (int j = 0; j < 4; ++j) {
    int lin = j * 256 + t;
    int row = lin >> 4, c4 = lin & 15;
    float4 v = *(const float4*)(src + (i0 + row) * 256 + h0 + c4 * 4);
    tile[row][c4 * 4 + 0] = v.x; tile[row][c4 * 4 + 1] = v.y;
    tile[row][c4 * 4 + 2] = v.z; tile[row][c4 * 4 + 3] = v.w;
  }
  __syncthreads();
#pragma unroll
  for (int j = 0; j < 4; ++j) {
    int lin = j * 256 + t;
    int hrow = lin >> 4, i4 = lin & 15;
    int k = i0 + i4 * 4;           // 4 consecutive k, same 32-chunk
    int n = h0 + hrow;
    u16x4 u;
    u.x = f2bf(tile[i4 * 4 + 0][hrow]);
    u.y = f2bf(tile[i4 * 4 + 1][hrow]);
    u.z = f2bf(tile[i4 * 4 + 2][hrow]);
    u.w = f2bf(tile[i4 * 4 + 3][hrow]);
    *(u16x4*)(dst + (k >> 5) * 8192 + n * 32 + (k & 31)) = u;
  }
}

// ---------- main fused kernel ----------
// block = (subcarrier c, batch tile of 64). 4 waves; wave tile 64x64 via 4x4 of 16x16x32.
// LDS: sA 4 KB (x slice) | sB 16 KB (W slice) | sH1 33 KB (64x264 bf16) = 54272 B -> 3 blocks/CU
__global__ __launch_bounds__(256, 3) void rf_main_k(
    const u16* __restrict__ xb, const u16* __restrict__ w1t, const u16* __restrict__ w2t,
    const float* __restrict__ b1, const float* __restrict__ b2,
    const float* __restrict__ w3, const float* __restrict__ b3,
    float* __restrict__ out) {
  __shared__ u16 sA[64 * 32];          // [row 64][k 32], 16B blocks XOR-swizzled
  __shared__ u16 sB[256 * 32];         // [n 256][k 32], 16B blocks XOR-swizzled
  __shared__ u16 sH1[64 * 264];        // row-major, padded stride 264

  const int bid  = blockIdx.x;
  const int c    = bid & 255;
  const int tile = bid >> 8;
  const int b0   = tile * 64;
  const int t    = threadIdx.x;
  const int lane = t & 63;
  const int w    = t >> 6;
  const int l15  = lane & 15;
  const int quad = lane >> 4;
  const int sw   = (l15 >> 1) & 3;
  const int qsw  = quad ^ sw;          // swizzled 16B-block index for staged buffers

  // staging maps (swizzle applied on SOURCE so LDS dst stays base + lane*16)
  const int ar = t >> 2;                               // x row within tile
  const int aq = (t & 3) ^ ((t >> 3) & 3);             // swizzled k-block
  const u16* xrow = xb + (b0 + ar) * 256;

  f32x4 acc[4][4] = {};

  // ================= Phase A: H1 = relu(x @ W1[c] + b1) =================
  const u16* w1c = w1t + c * 65536;
#pragma unroll 1
  for (int ch = 0; ch < 8; ++ch) {
    __syncthreads();
    async16(xrow + ch * 32 + aq * 8, &sA[t * 8]);
    const u16* wc = w1c + ch * 8192;
#pragma unroll
    for (int j = 0; j < 4; ++j) {
      int lin = j * 256 + t;
      int n = j * 64 + (t >> 2);
      async16(wc + n * 32 + aq * 8, &sB[lin * 8]);
    }
    __syncthreads();
    bf16x8 af[4], bfr[4];
#pragma unroll
    for (int mi = 0; mi < 4; ++mi)
      af[mi] = *(const bf16x8*)&sA[(mi * 16 + l15) * 32 + qsw * 8];
#pragma unroll
    for (int ni = 0; ni < 4; ++ni) {
      int n = w * 64 + ni * 16 + l15;
      bfr[ni] = *(const bf16x8*)&sB[n * 32 + qsw * 8];
    }
#pragma unroll
    for (int mi = 0; mi < 4; ++mi)
#pragma unroll
      for (int ni = 0; ni < 4; ++ni)
        acc[mi][ni] = __builtin_amdgcn_mfma_f32_16x16x32_bf16(af[mi], bfr[ni], acc[mi][ni], 0, 0, 0);
  }

  // Phase A epilogue: bias+relu, C-layout -> row-major bf16 H1 in LDS
#pragma unroll
  for (int ni = 0; ni < 4; ++ni) {
    int col = w * 64 + ni * 16 + l15;
    float bias = b1[c * 256 + col];
#pragma unroll
    for (int mi = 0; mi < 4; ++mi)
#pragma unroll
      for (int r = 0; r < 4; ++r) {
        int row = mi * 16 + quad * 4 + r;
        float v = acc[mi][ni][r] + bias;
        v = v > 0.f ? v : 0.f;
        sH1[row * 264 + col] = f2bf(v);
        acc[mi][ni][r] = 0.f;          // reset for phase B
      }
  }

  // ================= Phase B: H2 = relu(H1 @ W2[c] + b2), fused W3 dot =================
  const u16* w2c = w2t + c * 65536;
#pragma unroll 1
  for (int ch = 0; ch < 8; ++ch) {
    __syncthreads();                   // first iter also publishes sH1
    const u16* wc = w2c + ch * 8192;
#pragma unroll
    for (int j = 0; j < 4; ++j) {
      int lin = j * 256 + t;
      int n = j * 64 + (t >> 2);
      async16(wc + n * 32 + aq * 8, &sB[lin * 8]);
    }
    __syncthreads();
    bf16x8 af[4], bfr[4];
#pragma unroll
    for (int mi = 0; mi < 4; ++mi)
      af[mi] = *(const bf16x8*)&sH1[(mi * 16 + l15) * 264 + ch * 32 + quad * 8];
#pragma unroll
    for (int ni = 0; ni < 4; ++ni) {
      int n = w * 64 + ni * 16 + l15;
      bfr[ni] = *(const bf16x8*)&sB[n * 32 + qsw * 8];
    }
#pragma unroll
    for (int mi = 0; mi < 4; ++mi)
#pragma unroll
      for (int ni = 0; ni < 4; ++ni)
        acc[mi][ni] = __builtin_amdgcn_mfma_f32_16x16x32_bf16(af[mi], bfr[ni], acc[mi][ni], 0, 0, 0);
  }

  // Phase B epilogue: out[b] = sum_h relu(acc+b2)*W3[h] + b3  (no H2 materialization)
  float part[16];
#pragma unroll
  for (int i = 0; i < 16; ++i) part[i] = 0.f;
#pragma unroll
  for (int ni = 0; ni < 4; ++ni) {
    int col = w * 64 + ni * 16 + l15;
    float bias = b2[c * 256 + col];
    float w3v  = w3[c * 256 + col];
#pragma unroll
    for (int mi = 0; mi < 4; ++mi)
#pragma unroll
      for (int r = 0; r < 4; ++r) {
        float v = acc[mi][ni][r] + bias;
        v = v > 0.f ? v : 0.f;
        part[mi * 4 + r] += v * w3v;
      }
  }
  // reduce over the 16 lanes of each quad-group (they share rows, cover all 64 cols)
#pragma unroll
  for (int m = 1; m < 16; m <<= 1)
#pragma unroll
    for (int i = 0; i < 16; ++i)
      part[i] += __shfl_xor(part[i], m, 64);

  float* red = (float*)sA;             // sA dead after phase A
  if (l15 == 0) {
#pragma unroll
    for (int mi = 0; mi < 4; ++mi)
#pragma unroll
      for (int r = 0; r < 4; ++r)
        red[w * 64 + mi * 16 + quad * 4 + r] = part[mi * 4 + r];
  }
  __syncthreads();
  if (t < 64) {
    float v = red[t] + red[64 + t] + red[128 + t] + red[192 + t] + b3[c];
    out[(b0 + t) * 256 + c] = v;
  }
}

// ---------- launcher ----------
extern "C" void kernel_launch(void* const* d_in, const int* in_sizes, int n_in,
                              void* d_out, int out_size, void* d_ws, size_t ws_size,
                              hipStream_t stream) {
  const float* x  = (const float*)d_in[0];
  const float* W1 = (const float*)d_in[1];
  const float* b1 = (const float*)d_in[2];
  const float* W2 = (const float*)d_in[3];
  const float* b2 = (const float*)d_in[4];
  const float* W3 = (const float*)d_in[5];
  const float* b3 = (const float*)d_in[6];
  float* out = (float*)d_out;

  char* ws = (char*)d_ws;
  u16* xb  = (u16*)ws;                                   // 1 MB
  u16* w1t = (u16*)(ws + (1u << 20));                    // 32 MB
  u16* w2t = (u16*)(ws + (1u << 20) + (32u << 20));      // 32 MB  (total 65 MB)

  convert_x_k  <<<512,  256, 0, stream>>>(x,  xb);
  transpose_w_k<<<4096, 256, 0, stream>>>(W1, w1t);
  transpose_w_k<<<4096, 256, 0, stream>>>(W2, w2t);
  rf_main_k    <<<8192, 256, 0, stream>>>(xb, w1t, w2t, b1, b2, W3, b3, out);
}

// Round 2
// 398.629 us; speedup vs baseline: 1.0157x; 1.0157x over previous
//
#include <hip/hip_runtime.h>

typedef unsigned short u16;
using u16x4  = __attribute__((ext_vector_type(4))) unsigned short;
using u16x8  = __attribute__((ext_vector_type(8))) unsigned short;
using bf16x8 = __attribute__((ext_vector_type(8))) short;
using f32x4  = __attribute__((ext_vector_type(4))) float;

// ---------- helpers ----------
__device__ __forceinline__ u16 f2bf(float f) {
  union { float f; unsigned u; } v; v.f = f;
  unsigned r = v.u + 0x7FFFu + ((v.u >> 16) & 1u);  // RNE (inputs bounded, no NaN)
  return (u16)(r >> 16);
}

__device__ __forceinline__ void async16(const u16* g, u16* l) {
  __builtin_amdgcn_global_load_lds(
      (const __attribute__((address_space(1))) void*)g,
      (__attribute__((address_space(3))) void*)l, 16, 0, 0);
}

// ---------- pre-pass 1: x fp32 -> bf16 ----------
__global__ void convert_x_k(const float* __restrict__ in, u16* __restrict__ out) {
  int i = blockIdx.x * 256 + threadIdx.x;      // one float4 per thread, 512 blocks
  float4 v = ((const float4*)in)[i];
  u16x4 u;
  u.x = f2bf(v.x); u.y = f2bf(v.y); u.z = f2bf(v.z); u.w = f2bf(v.w);
  ((u16x4*)out)[i] = u;
}

// ---------- pre-pass 2: both W tensors [mat][i][h] fp32 -> blocked bf16 [mat][i/32][h][32] ----------
// One launch, fully-coalesced 16B/lane stores. 8192 blocks: mat = bid>>4 (0..511), 16 64x64 tiles.
__global__ __launch_bounds__(256) void transpose_w2_k(
    const float* __restrict__ W1, const float* __restrict__ W2,
    u16* __restrict__ w1t, u16* __restrict__ w2t) {
  __shared__ float tile[64][65];
  const int bid = blockIdx.x;
  const int mat = bid >> 4;
  const int tl  = bid & 15;
  const int i0 = (tl >> 2) * 64, h0 = (tl & 3) * 64;
  const float* src = (mat < 256) ? (W1 + mat * 65536) : (W2 + (mat - 256) * 65536);
  u16*       dst   = (mat < 256) ? (w1t + mat * 65536) : (w2t + (mat - 256) * 65536);
  const int t = threadIdx.x;
#pragma unroll
  for (int j = 0; j < 4; ++j) {
    int lin = j * 256 + t;
    int row = lin >> 4, c4 = lin & 15;
    float4 v = *(const float4*)(src + (i0 + row) * 256 + h0 + c4 * 4);
    tile[row][c4 * 4 + 0] = v.x; tile[row][c4 * 4 + 1] = v.y;
    tile[row][c4 * 4 + 2] = v.z; tile[row][c4 * 4 + 3] = v.w;
  }
  __syncthreads();
  // thread t writes 8 contiguous u16: n = h0 + t/4 (col), k-octet (t&3)*8 within chunk
  const int col = t >> 2;            // 0..63 -> n = h0+col
  const int kk  = (t & 3) * 8;
#pragma unroll
  for (int p = 0; p < 2; ++p) {      // two 32-wide k-chunks per 64-row tile
    u16x8 o;
#pragma unroll
    for (int jj = 0; jj < 8; ++jj)
      o[jj] = f2bf(tile[p * 32 + kk + jj][col]);
    *(u16x8*)(dst + ((i0 >> 5) + p) * 8192 + (h0 + col) * 32 + kk) = o;
  }
}

// ---------- main fused kernel ----------
// block = (subcarrier c, batch tile of 64). 4 waves; wave tile 64x64 via 4x4 of 16x16x32.
// XCD-affine mapping: xcd = bid&7 owns c in [xcd*32, xcd*32+32), tiles of one c back-to-back
// -> W[c] (256 KB bf16) stays L2-resident across its 32 batch tiles.
// Double-buffered staging: prefetch chunk k+1 right after the barrier publishing chunk k.
// LDS: sA 2x4KB | sB 2x16KB | sH1 33KB = 74752 B -> 2 blocks/CU (8 waves).
__global__ __launch_bounds__(256, 2) void rf_main_k(
    const u16* __restrict__ xb, const u16* __restrict__ w1t, const u16* __restrict__ w2t,
    const float* __restrict__ b1, const float* __restrict__ b2,
    const float* __restrict__ w3, const float* __restrict__ b3,
    float* __restrict__ out) {
  __shared__ u16 sA[2][64 * 32];       // [row 64][k 32], 16B blocks XOR-swizzled
  __shared__ u16 sB[2][256 * 32];      // [n 256][k 32], 16B blocks XOR-swizzled
  __shared__ u16 sH1[64 * 264];        // row-major, padded stride 264

  const int bid  = blockIdx.x;
  const int xcd  = bid & 7;
  const int j8   = bid >> 3;           // 0..1023
  const int c    = xcd * 32 + (j8 >> 5);
  const int tile = j8 & 31;
  const int b0   = tile * 64;
  const int t    = threadIdx.x;
  const int lane = t & 63;
  const int w    = t >> 6;
  const int l15  = lane & 15;
  const int quad = lane >> 4;
  const int sw   = (l15 >> 1) & 3;
  const int qsw  = quad ^ sw;          // swizzled 16B-block index for staged buffers

  // staging maps (swizzle applied on SOURCE so LDS dst stays base + lane*16)
  const int ar = t >> 2;                               // x row within tile
  const int aq = (t & 3) ^ ((t >> 3) & 3);             // swizzled k-block
  const u16* xrow = xb + (b0 + ar) * 256;
  const u16* w1c = w1t + c * 65536;
  const u16* w2c = w2t + c * 65536;

  f32x4 acc[4][4] = {};

#define STAGE_A(ch, buf) async16(xrow + (ch) * 32 + aq * 8, &sA[buf][t * 8])
#define STAGE_B(wc, ch, buf)                                            \
  {                                                                     \
    const u16* _w = (wc) + (ch) * 8192;                                 \
    _Pragma("unroll")                                                   \
    for (int _j = 0; _j < 4; ++_j) {                                    \
      int _n = _j * 64 + (t >> 2);                                      \
      async16(_w + _n * 32 + aq * 8, &sB[buf][(_j * 256 + t) * 8]);     \
    }                                                                   \
  }

  // prefetch chunk 0
  STAGE_A(0, 0);
  STAGE_B(w1c, 0, 0);

  // ================= Phase A: H1 = relu(x @ W1[c] + b1) =================
#pragma unroll
  for (int ch = 0; ch < 8; ++ch) {
    const int cur = ch & 1, nxt = (ch + 1) & 1;
    __syncthreads();                   // drains chunk-ch loads
    if (ch < 7) {
      STAGE_A(ch + 1, nxt);
      STAGE_B(w1c, ch + 1, nxt);
    } else {
      STAGE_B(w2c, 0, nxt);            // head start on phase B chunk 0 (nxt == 0)
    }
    bf16x8 af[4], bfr[4];
#pragma unroll
    for (int mi = 0; mi < 4; ++mi)
      af[mi] = *(const bf16x8*)&sA[cur][(mi * 16 + l15) * 32 + qsw * 8];
#pragma unroll
    for (int ni = 0; ni < 4; ++ni) {
      int n = w * 64 + ni * 16 + l15;
      bfr[ni] = *(const bf16x8*)&sB[cur][n * 32 + qsw * 8];
    }
#pragma unroll
    for (int mi = 0; mi < 4; ++mi)
#pragma unroll
      for (int ni = 0; ni < 4; ++ni)
        acc[mi][ni] = __builtin_amdgcn_mfma_f32_16x16x32_bf16(af[mi], bfr[ni], acc[mi][ni], 0, 0, 0);
  }

  // Phase A epilogue: bias+relu, C-layout -> row-major bf16 H1 in LDS
#pragma unroll
  for (int ni = 0; ni < 4; ++ni) {
    int col = w * 64 + ni * 16 + l15;
    float bias = b1[c * 256 + col];
#pragma unroll
    for (int mi = 0; mi < 4; ++mi)
#pragma unroll
      for (int r = 0; r < 4; ++r) {
        int row = mi * 16 + quad * 4 + r;
        float v = acc[mi][ni][r] + bias;
        v = v > 0.f ? v : 0.f;
        sH1[row * 264 + col] = f2bf(v);
        acc[mi][ni][r] = 0.f;          // reset for phase B
      }
  }

  // ================= Phase B: H2 = relu(H1 @ W2[c] + b2), fused W3 dot =================
#pragma unroll
  for (int ch = 0; ch < 8; ++ch) {
    const int cur = ch & 1, nxt = (ch + 1) & 1;
    __syncthreads();                   // ch=0 also publishes sH1 + drains B chunk-0 loads
    if (ch < 7) STAGE_B(w2c, ch + 1, nxt);
    bf16x8 af[4], bfr[4];
#pragma unroll
    for (int mi = 0; mi < 4; ++mi)
      af[mi] = *(const bf16x8*)&sH1[(mi * 16 + l15) * 264 + ch * 32 + quad * 8];
#pragma unroll
    for (int ni = 0; ni < 4; ++ni) {
      int n = w * 64 + ni * 16 + l15;
      bfr[ni] = *(const bf16x8*)&sB[cur][n * 32 + qsw * 8];
    }
#pragma unroll
    for (int mi = 0; mi < 4; ++mi)
#pragma unroll
      for (int ni = 0; ni < 4; ++ni)
        acc[mi][ni] = __builtin_amdgcn_mfma_f32_16x16x32_bf16(af[mi], bfr[ni], acc[mi][ni], 0, 0, 0);
  }

  // Phase B epilogue: out[b] = sum_h relu(acc+b2)*W3[h] + b3  (no H2 materialization)
  float part[16];
#pragma unroll
  for (int i = 0; i < 16; ++i) part[i] = 0.f;
#pragma unroll
  for (int ni = 0; ni < 4; ++ni) {
    int col = w * 64 + ni * 16 + l15;
    float bias = b2[c * 256 + col];
    float w3v  = w3[c * 256 + col];
#pragma unroll
    for (int mi = 0; mi < 4; ++mi)
#pragma unroll
      for (int r = 0; r < 4; ++r) {
        float v = acc[mi][ni][r] + bias;
        v = v > 0.f ? v : 0.f;
        part[mi * 4 + r] += v * w3v;
      }
  }
  // reduce over the 16 lanes of each quad-group (they share rows, cover all 64 cols)
#pragma unroll
  for (int m = 1; m < 16; m <<= 1)
#pragma unroll
    for (int i = 0; i < 16; ++i)
      part[i] += __shfl_xor(part[i], m, 64);

  float* red = (float*)sA[0];          // sA dead after phase A
  if (l15 == 0) {
#pragma unroll
    for (int mi = 0; mi < 4; ++mi)
#pragma unroll
      for (int r = 0; r < 4; ++r)
        red[w * 64 + mi * 16 + quad * 4 + r] = part[mi * 4 + r];
  }
  __syncthreads();
  if (t < 64) {
    float v = red[t] + red[64 + t] + red[128 + t] + red[192 + t] + b3[c];
    out[(b0 + t) * 256 + c] = v;
  }
#undef STAGE_A
#undef STAGE_B
}

// ---------- launcher ----------
extern "C" void kernel_launch(void* const* d_in, const int* in_sizes, int n_in,
                              void* d_out, int out_size, void* d_ws, size_t ws_size,
                              hipStream_t stream) {
  const float* x  = (const float*)d_in[0];
  const float* W1 = (const float*)d_in[1];
  const float* b1 = (const float*)d_in[2];
  const float* W2 = (const float*)d_in[3];
  const float* b2 = (const float*)d_in[4];
  const float* W3 = (const float*)d_in[5];
  const float* b3 = (const float*)d_in[6];
  float* out = (float*)d_out;

  char* ws = (char*)d_ws;
  u16* xb  = (u16*)ws;                                   // 1 MB
  u16* w1t = (u16*)(ws + (1u << 20));                    // 32 MB
  u16* w2t = (u16*)(ws + (1u << 20) + (32u << 20));      // 32 MB  (total 65 MB)

  convert_x_k  <<<512,  256, 0, stream>>>(x,  xb);
  transpose_w2_k<<<8192, 256, 0, stream>>>(W1, W2, w1t, w2t);
  rf_main_k    <<<8192, 256, 0, stream>>>(xb, w1t, w2t, b1, b2, W3, b3, out);
}

// Round 4
// 315.323 us; speedup vs baseline: 1.2840x; 1.2642x over previous
//
#include <hip/hip_runtime.h>

typedef unsigned short u16;
using u16x4  = __attribute__((ext_vector_type(4))) unsigned short;
using u16x8  = __attribute__((ext_vector_type(8))) unsigned short;
using bf16x8 = __attribute__((ext_vector_type(8))) short;
using f32x4  = __attribute__((ext_vector_type(4))) float;

// ---------- helpers ----------
__device__ __forceinline__ u16 f2bf(float f) {
  union { float f; unsigned u; } v; v.f = f;
  unsigned r = v.u + 0x7FFFu + ((v.u >> 16) & 1u);  // RNE (inputs bounded, no NaN)
  return (u16)(r >> 16);
}

// ---------- pre-pass 1: x fp32 -> bf16 ----------
// x is 2048*256 fp32 = 131072 float4 -> EXACTLY 512 blocks of 256 threads.
__global__ void convert_x_k(const float* __restrict__ in, u16* __restrict__ out) {
  int i = blockIdx.x * 256 + threadIdx.x;
  float4 v = ((const float4*)in)[i];
  u16x4 u;
  u.x = f2bf(v.x); u.y = f2bf(v.y); u.z = f2bf(v.z); u.w = f2bf(v.w);
  ((u16x4*)out)[i] = u;
}

// ---------- pre-pass 2: both W tensors [mat][i][h] fp32 -> blocked bf16 [mat][i/32][h][32] ----------
__global__ __launch_bounds__(256) void transpose_w2_k(
    const float* __restrict__ W1, const float* __restrict__ W2,
    u16* __restrict__ w1t, u16* __restrict__ w2t) {
  __shared__ float tile[64][65];
  const int bid = blockIdx.x;
  const int mat = bid >> 4;
  const int tl  = bid & 15;
  const int i0 = (tl >> 2) * 64, h0 = (tl & 3) * 64;
  const float* src = (mat < 256) ? (W1 + mat * 65536) : (W2 + (mat - 256) * 65536);
  u16*       dst   = (mat < 256) ? (w1t + mat * 65536) : (w2t + (mat - 256) * 65536);
  const int t = threadIdx.x;
#pragma unroll
  for (int j = 0; j < 4; ++j) {
    int lin = j * 256 + t;
    int row = lin >> 4, c4 = lin & 15;
    float4 v = *(const float4*)(src + (i0 + row) * 256 + h0 + c4 * 4);
    tile[row][c4 * 4 + 0] = v.x; tile[row][c4 * 4 + 1] = v.y;
    tile[row][c4 * 4 + 2] = v.z; tile[row][c4 * 4 + 3] = v.w;
  }
  __syncthreads();
  const int col = t >> 2;            // n = h0 + col
  const int kk  = (t & 3) * 8;
#pragma unroll
  for (int p = 0; p < 2; ++p) {      // two 32-wide k-chunks per 64-row tile
    u16x8 o;
#pragma unroll
    for (int jj = 0; jj < 8; ++jj)
      o[jj] = f2bf(tile[p * 32 + kk + jj][col]);
    *(u16x8*)(dst + ((i0 >> 5) + p) * 8192 + (h0 + col) * 32 + kk) = o;
  }
}

// ---------- main fused kernel ----------
// Block = (subcarrier c, 128-row batch tile). 512 threads = 8 waves, wave tile 64x64:
// waves 0-3 rows 0-63 (cols 0/64/128/192), waves 4-7 rows 64-127.
// B-fragments load DIRECT global->VGPR (1 KB contiguous per wave per frag, L2-resident via
// XCD-affine mapping) -- no LDS staging, NO barriers inside the K-loops.
// x-tile staged once into sH (padded stride 264); H1 overwrites sH in place (2 barriers).
// LDS 69.6 KB -> 2 blocks/CU = 16 waves/CU.
__global__ __launch_bounds__(512, 4) void rf_main_k(
    const u16* __restrict__ xb, const u16* __restrict__ w1t, const u16* __restrict__ w2t,
    const float* __restrict__ b1, const float* __restrict__ b2,
    const float* __restrict__ w3, const float* __restrict__ b3,
    float* __restrict__ out) {
  __shared__ u16 sH[128 * 264];        // x-tile, then H1 (in place), stride 264
  __shared__ float red[512];           // 8 waves x 64 rows

  const int bid  = blockIdx.x;
  const int xcd  = bid & 7;
  const int j8   = bid >> 3;           // 0..511
  const int c    = xcd * 32 + (j8 >> 4);
  const int b0   = (j8 & 15) * 128;
  const int t    = threadIdx.x;
  const int lane = t & 63;
  const int w    = t >> 6;
  const int l15  = lane & 15;
  const int quad = lane >> 4;
  const int half = w >> 2;             // row half (0: rows 0-63, 1: rows 64-127)
  const int nw   = (w & 3) * 64;       // col base

  const u16* w1c = w1t + c * 65536;
  const u16* w2c = w2t + c * 65536;
  // per-lane fragment offsets
  const int boff  = (nw + l15) * 32 + quad * 8;              // + ch*8192 + ni*512 (global B)
  const int abase = (half * 64 + l15) * 264 + quad * 8;      // + mi*16*264 + ch*32 (LDS A)

  f32x4  acc[4][4] = {};
  bf16x8 bA[4], bB[4];

#define LOADB(dst, base)                                        \
  { _Pragma("unroll")                                           \
    for (int _n = 0; _n < 4; ++_n)                              \
      dst[_n] = *(const bf16x8*)((base) + _n * 512); }

#define COMPUTE(bfr, ch)                                        \
  { _Pragma("unroll")                                           \
    for (int _m = 0; _m < 4; ++_m) {                            \
      bf16x8 _a = *(const bf16x8*)&sH[abase + _m * (16*264) + (ch) * 32]; \
      _Pragma("unroll")                                         \
      for (int _n = 0; _n < 4; ++_n)                            \
        acc[_m][_n] = __builtin_amdgcn_mfma_f32_16x16x32_bf16(_a, bfr[_n], acc[_m][_n], 0, 0, 0); \
    } }

  // prefetch W1 chunk 0 while staging x
  LOADB(bA, w1c + boff);

  // stage x-tile: 128 rows x 256 u16 -> sH stride 264 (one time)
#pragma unroll
  for (int i = 0; i < 8; ++i) {
    int flat = i * 512 + t;
    int r = flat >> 5, s = flat & 31;
    u16x8 g = *(const u16x8*)(xb + (b0 + r) * 256 + s * 8);
    *(u16x8*)&sH[r * 264 + s * 8] = g;
  }
  __syncthreads();

  // ========== Phase A: H1 = relu(x @ W1[c] + b1), barrier-free K-loop ==========
#pragma unroll 1
  for (int ch = 0; ch < 8; ch += 2) {
    LOADB(bB, w1c + (ch + 1) * 8192 + boff);
    COMPUTE(bA, ch);
    const u16* nxt = (ch == 6) ? (w2c + boff)                    // phase-B ch0 prefetch
                               : (w1c + (ch + 2) * 8192 + boff);
    LOADB(bA, nxt);
    COMPUTE(bB, ch + 1);
  }

  // Phase A epilogue: bias+relu -> bf16 H1, in place over sX
  __syncthreads();                     // all sX reads retired
#pragma unroll
  for (int ni = 0; ni < 4; ++ni) {
    int col = nw + ni * 16 + l15;
    float bias = b1[c * 256 + col];
#pragma unroll
    for (int mi = 0; mi < 4; ++mi)
#pragma unroll
      for (int r = 0; r < 4; ++r) {
        int row = half * 64 + mi * 16 + quad * 4 + r;
        float v = acc[mi][ni][r] + bias;
        v = v > 0.f ? v : 0.f;
        sH[row * 264 + col] = f2bf(v);
        acc[mi][ni][r] = 0.f;
      }
  }
  __syncthreads();                     // H1 published

  // ========== Phase B: relu(H1 @ W2[c] + b2) . W3, barrier-free K-loop ==========
#pragma unroll 1
  for (int ch = 0; ch < 8; ch += 2) {
    LOADB(bB, w2c + (ch + 1) * 8192 + boff);
    COMPUTE(bA, ch);
    if (ch < 6) LOADB(bA, w2c + (ch + 2) * 8192 + boff);
    COMPUTE(bB, ch + 1);
  }

  // Phase B epilogue: out = relu(acc + b2) . W3 + b3
  float part[16];
#pragma unroll
  for (int i = 0; i < 16; ++i) part[i] = 0.f;
#pragma unroll
  for (int ni = 0; ni < 4; ++ni) {
    int col = nw + ni * 16 + l15;
    float bias = b2[c * 256 + col];
    float w3v  = w3[c * 256 + col];
#pragma unroll
    for (int mi = 0; mi < 4; ++mi)
#pragma unroll
      for (int r = 0; r < 4; ++r) {
        float v = acc[mi][ni][r] + bias;
        v = v > 0.f ? v : 0.f;
        part[mi * 4 + r] += v * w3v;
      }
  }
#pragma unroll
  for (int m = 1; m < 16; m <<= 1)
#pragma unroll
    for (int i = 0; i < 16; ++i)
      part[i] += __shfl_xor(part[i], m, 64);

  if (l15 == 0) {
#pragma unroll
    for (int mi = 0; mi < 4; ++mi)
#pragma unroll
      for (int r = 0; r < 4; ++r)
        red[w * 64 + mi * 16 + quad * 4 + r] = part[mi * 4 + r];
  }
  __syncthreads();
  if (t < 128) {
    int hr = t >> 6, rr = t & 63;
    float v = red[(hr * 4 + 0) * 64 + rr] + red[(hr * 4 + 1) * 64 + rr] +
              red[(hr * 4 + 2) * 64 + rr] + red[(hr * 4 + 3) * 64 + rr] + b3[c];
    out[(b0 + t) * 256 + c] = v;
  }
#undef LOADB
#undef COMPUTE
}

// ---------- launcher ----------
extern "C" void kernel_launch(void* const* d_in, const int* in_sizes, int n_in,
                              void* d_out, int out_size, void* d_ws, size_t ws_size,
                              hipStream_t stream) {
  const float* x  = (const float*)d_in[0];
  const float* W1 = (const float*)d_in[1];
  const float* b1 = (const float*)d_in[2];
  const float* W2 = (const float*)d_in[3];
  const float* b2 = (const float*)d_in[4];
  const float* W3 = (const float*)d_in[5];
  const float* b3 = (const float*)d_in[6];
  float* out = (float*)d_out;

  char* ws = (char*)d_ws;
  u16* xb  = (u16*)ws;                                   // 1 MB
  u16* w1t = (u16*)(ws + (1u << 20));                    // 32 MB
  u16* w2t = (u16*)(ws + (1u << 20) + (32u << 20));      // 32 MB

  convert_x_k   <<<512,  256, 0, stream>>>(x,  xb);      // 512*256 threads == 131072 float4 == |x|/4
  transpose_w2_k<<<8192, 256, 0, stream>>>(W1, W2, w1t, w2t);
  rf_main_k     <<<4096, 512, 0, stream>>>(xb, w1t, w2t, b1, b2, W3, b3, out);
}